// Round 8
// baseline (304.474 us; speedup 1.0000x reference)
//
#include <hip/hip_runtime.h>
#include <hip/hip_bf16.h>

typedef __bf16 v4bf __attribute__((ext_vector_type(4)));
typedef __bf16 v8bf __attribute__((ext_vector_type(8)));
typedef float  v16f __attribute__((ext_vector_type(16)));
typedef float  f4v  __attribute__((ext_vector_type(4)));
typedef unsigned int u4v __attribute__((ext_vector_type(4)));

#define LOG2E 1.44269504088896340736f

// round-to-nearest-even float -> bf16 bits
__device__ __forceinline__ unsigned short f2bf(float f) {
    union { float f; unsigned int u; } a; a.f = f;
    unsigned int r = a.u + 0x7FFFu + ((a.u >> 16) & 1u);
    return (unsigned short)(r >> 16);
}

__device__ __forceinline__ void unpack8v(u4v w, float* f) {
    #pragma unroll
    for (int i = 0; i < 4; ++i) {
        f[2 * i]     = __uint_as_float(w[i] << 16);
        f[2 * i + 1] = __uint_as_float(w[i] & 0xFFFF0000u);
    }
}

// ---------------- Phase 0: pack W^T bf16 + zero deg (fused) ----------------
// k & q weights pre-scaled by log2(e); k additionally NEGATED so the
// gather kernel reads nk = -k' directly (sigmoid = rcp(1 + 2^(nk - q'))).
__global__ __launch_bounds__(256) void prep_w_zero(
    const float* __restrict__ Wk, const float* __restrict__ Wq,
    const float* __restrict__ Wv, const float* __restrict__ Ws,
    unsigned short* __restrict__ Wt, int* __restrict__ deg, int N)
{
    int i = blockIdx.x * 256 + threadIdx.x;      // 512 blocks -> 131072 threads
    if (i < 65536) {
        int m = i >> 14;
        int r = i & 16383;
        int n = r >> 7, k = r & 127;
        const float* W = (m == 0) ? Wk : (m == 1) ? Wq : (m == 2) ? Wv : Ws;
        float scale = (m == 0) ? -LOG2E : (m == 1) ? LOG2E : 1.0f;
        Wt[i] = f2bf(W[k * 128 + n] * scale);
    }
    if (i < N) deg[i] = 0;
}

// ---------------- Phase 1: fused MFMA GEMM + edge counting ----------------
// R7 post-mortem: old shape ran at 2 TB/s with nothing saturated — 16
// scalar 2B stores/thread + vmcnt(0) barrier drain every 32-row tile.
// New shape: 128-row tile, ONE tile per block (no loop, no prefetch, one
// natural drain), SWAPPED-operand MFMA (computes out^T fragment) so each
// lane owns one ROW and 4-reg groups are 4 CONTIGUOUS cols -> epilogue is
// 4 vector stores (8B bf16 / 16B f32) per rt instead of 16 scalar stores.
// Edge degree-count (VMEM/atomic) fused at head, hides under the GEMM.
__global__ __launch_bounds__(1024, 4) void gemm_fused(
    const float* __restrict__ x, int N,
    const unsigned short* __restrict__ Wt,
    const float* __restrict__ bk, const float* __restrict__ bq,
    const float* __restrict__ bv, const float* __restrict__ bs,
    unsigned short* __restrict__ kws, unsigned short* __restrict__ qv,
    float* __restrict__ out,
    const int* __restrict__ ei, int E,
    int* __restrict__ deg, int* __restrict__ pos)
{
    // fused counting-sort pass 1 (one edge per thread; grid covers E)
    for (int e = blockIdx.x * 1024 + threadIdx.x; e < E; e += gridDim.x * 1024) {
        pos[e] = atomicAdd(&deg[ei[E + e]], 1);   // dst
    }

    __shared__ __align__(16) unsigned short xs[128 * 132];
    const int t  = threadIdx.x;
    const int tb = blockIdx.x * 128;             // tile base row

    // ---- stage 128x128 x-tile as bf16 (thread: 1 row, 16 cols) ----
    {
        const int srow = t >> 3;                 // 0..127
        const int scol = (t & 7) << 4;           // 0,16,...,112
        const int gr = tb + srow;
        float4 f0, f1, f2, f3;
        if (gr < N) {
            const float* xp = x + (size_t)gr * 128 + scol;
            f0 = *(const float4*)(xp);
            f1 = *(const float4*)(xp + 4);
            f2 = *(const float4*)(xp + 8);
            f3 = *(const float4*)(xp + 12);
        } else {
            f0 = f1 = f2 = f3 = make_float4(0.f, 0.f, 0.f, 0.f);
        }
        unsigned short* sp = xs + srow * 132 + scol;
        ushort4 p;
        p.x = f2bf(f0.x); p.y = f2bf(f0.y); p.z = f2bf(f0.z); p.w = f2bf(f0.w);
        *(ushort4*)(sp) = p;
        p.x = f2bf(f1.x); p.y = f2bf(f1.y); p.z = f2bf(f1.z); p.w = f2bf(f1.w);
        *(ushort4*)(sp + 4) = p;
        p.x = f2bf(f2.x); p.y = f2bf(f2.y); p.z = f2bf(f2.z); p.w = f2bf(f2.w);
        *(ushort4*)(sp + 8) = p;
        p.x = f2bf(f3.x); p.y = f2bf(f3.y); p.z = f2bf(f3.z); p.w = f2bf(f3.w);
        *(ushort4*)(sp + 12) = p;
    }

    const int wid = t >> 6;          // 0..15
    const int m   = wid >> 2;        // matrix
    const int ct  = wid & 3;         // col tile
    const int l   = t & 63;
    const int lr  = l & 31;          // lane row/col-in-tile index
    const int h   = l >> 5;          // half-wave
    const int kb  = h * 8;

    // W fragments (A-operand of the swapped MFMA), loaded once
    v8bf b[8];
    {
        const unsigned short* wp = Wt + m * 16384 + (ct * 32 + lr) * 128 + kb;
        #pragma unroll
        for (int c = 0; c < 8; ++c) b[c] = *(const v8bf*)(wp + c * 16);
    }
    const float* bvec = (m == 0) ? bk : (m == 1) ? bq : (m == 2) ? bv : bs;
    const float bscale = (m == 0) ? -LOG2E : (m == 1) ? LOG2E : 1.0f;
    // per-group bias (4 contiguous cols each): col = ct*32 + 8g + 4h + 0..3
    float4 biasg[4];
    #pragma unroll
    for (int g = 0; g < 4; ++g) {
        float4 bb = *(const float4*)(bvec + ct * 32 + 8 * g + 4 * h);
        biasg[g] = make_float4(bb.x * bscale, bb.y * bscale, bb.z * bscale, bb.w * bscale);
    }
    unsigned short* dst; int dstride;
    if (m == 0)      { dst = kws;      dstride = 128; }
    else if (m == 1) { dst = qv;       dstride = 256; }
    else             { dst = qv + 128; dstride = 256; }   // m==2 (v half)

    __syncthreads();

    // ---- 4 row-subtiles of 32: swapped-operand MFMA + vector stores ----
    #pragma unroll
    for (int rt = 0; rt < 4; ++rt) {
        const unsigned short* ap = xs + (rt * 32 + lr) * 132 + kb;
        v16f acc = {};
        #pragma unroll
        for (int c = 0; c < 8; ++c) {
            v4bf a0 = *(const v4bf*)(ap + c * 16);
            v4bf a1 = *(const v4bf*)(ap + c * 16 + 4);
            v8bf a = __builtin_shufflevector(a0, a1, 0, 1, 2, 3, 4, 5, 6, 7);
            acc = __builtin_amdgcn_mfma_f32_32x32x16_bf16(b[c], a, acc, 0, 0, 0);
        }
        // D' = out^T fragment: lane owns row tb+rt*32+lr; reg group g ->
        // cols ct*32 + 8g + 4h + 0..3 (contiguous)
        const int row = tb + rt * 32 + lr;
        if (row < N) {
            if (m == 3) {
                float* orow = out + (size_t)row * 128 + ct * 32 + 4 * h;
                #pragma unroll
                for (int g = 0; g < 4; ++g) {
                    float4 o;
                    o.x = acc[4 * g + 0] + biasg[g].x;
                    o.y = acc[4 * g + 1] + biasg[g].y;
                    o.z = acc[4 * g + 2] + biasg[g].z;
                    o.w = acc[4 * g + 3] + biasg[g].w;
                    *(float4*)(orow + 8 * g) = o;
                }
            } else {
                unsigned short* drow = dst + (size_t)row * dstride + ct * 32 + 4 * h;
                #pragma unroll
                for (int g = 0; g < 4; ++g) {
                    ushort4 p;
                    p.x = f2bf(acc[4 * g + 0] + biasg[g].x);
                    p.y = f2bf(acc[4 * g + 1] + biasg[g].y);
                    p.z = f2bf(acc[4 * g + 2] + biasg[g].z);
                    p.w = f2bf(acc[4 * g + 3] + biasg[g].w);
                    *(ushort4*)(drow + 8 * g) = p;
                }
            }
        }
    }
}

// ---------------- Phase 2: CSR finish (scan + scatter, atomic-free) ----------------

__global__ __launch_bounds__(256) void scan_chunks(
    const int* __restrict__ deg, int N, int* __restrict__ rowStart,
    int* __restrict__ chunkTot)
{
    __shared__ int sums[256];
    const int t = threadIdx.x;
    const int base = blockIdx.x * 1024 + t * 4;
    int d0 = 0, d1 = 0, d2 = 0, d3 = 0;
    if (base + 3 < N) {
        int4 dd = *(const int4*)(deg + base);
        d0 = dd.x; d1 = dd.y; d2 = dd.z; d3 = dd.w;
    } else {
        if (base + 0 < N) d0 = deg[base + 0];
        if (base + 1 < N) d1 = deg[base + 1];
        if (base + 2 < N) d2 = deg[base + 2];
        if (base + 3 < N) d3 = deg[base + 3];
    }
    int tot = d0 + d1 + d2 + d3;
    sums[t] = tot;
    __syncthreads();
    #pragma unroll
    for (int off = 1; off < 256; off <<= 1) {
        int v = (t >= off) ? sums[t - off] : 0;
        __syncthreads();
        sums[t] += v;
        __syncthreads();
    }
    int excl = sums[t] - tot;
    if (base + 0 < N) rowStart[base + 0] = excl;
    if (base + 1 < N) rowStart[base + 1] = excl + d0;
    if (base + 2 < N) rowStart[base + 2] = excl + d0 + d1;
    if (base + 3 < N) rowStart[base + 3] = excl + d0 + d1 + d2;
    if (t == 255) chunkTot[blockIdx.x] = sums[255];
}

// add chunk offsets; each block re-scans the (<=128) chunk totals in LDS
__global__ __launch_bounds__(256) void add_offsets(
    int* __restrict__ rowStart, const int* __restrict__ chunkTot,
    int N, int nChunks)
{
    __shared__ int s[128];
    const int t = threadIdx.x;
    if (t < 128) s[t] = (t < nChunks) ? chunkTot[t] : 0;
    __syncthreads();
    #pragma unroll
    for (int off = 1; off < 128; off <<= 1) {
        int u = 0;
        if (t < 128 && t >= off) u = s[t - off];
        __syncthreads();
        if (t < 128) s[t] += u;
        __syncthreads();
    }
    const int coff = (blockIdx.x == 0) ? 0 : s[blockIdx.x - 1];
    const int base = blockIdx.x * 1024 + t * 4;
    if (base + 3 < N) {
        int4 r = *(const int4*)(rowStart + base);
        r.x += coff; r.y += coff; r.z += coff; r.w += coff;
        *(int4*)(rowStart + base) = r;
    } else {
        #pragma unroll
        for (int j = 0; j < 4; ++j) {
            if (base + j < N) rowStart[base + j] += coff;
        }
    }
}

__global__ __launch_bounds__(256) void fill_csr(
    const int* __restrict__ ei, int E,
    const int* __restrict__ rowStart, const int* __restrict__ pos,
    int* __restrict__ elist)
{
    int e = blockIdx.x * 256 + threadIdx.x;
    if (e >= E) return;
    elist[rowStart[ei[E + e]] + pos[e]] = ei[e];   // atomic-free scatter
}

// ---------------- Phase 3: owner-computes aggregation (no atomics) ----------------
// NATURAL node order (R6: perm indirection cost ~+15us at equal traffic).
// 4 nodes/wave (16 lanes each), lane owns 8 feats. Grid-stride persistent
// blocks; (256,8) bounds -> 8 waves/EU (VGPR<=64, measured fit exactly)
// for 2x the TLP of R7's 25%-occupancy config on this latency-bound loop.
// Exact-trip chunk-4 loop (clamped index, zeroed v for pad slots). out
// RMW hoisted to node start (natural order: WRITE=50MB, no amplification).
__global__ __launch_bounds__(256, 8) void gather_agg(
    const int* __restrict__ rowStart, const int* __restrict__ deg,
    const int* __restrict__ elist,
    const unsigned short* __restrict__ kws,
    const unsigned short* __restrict__ qv,
    float* __restrict__ out, int N)
{
    const int grp = threadIdx.x >> 4;            // 0..15 group within block
    const int fo  = (threadIdx.x & 15) << 3;     // 8 feats per lane
    const int gstride = gridDim.x * 16;
    const unsigned short* qvb = qv + fo;

    for (int node = blockIdx.x * 16 + grp; node < N; node += gstride) {
        // independent long-latency loads first
        float* orow = out + (size_t)node * 128 + fo;
        f4v o0 = *(const f4v*)(orow);
        f4v o1 = *(const f4v*)(orow + 4);
        u4v kraw = *(const u4v*)(kws + (size_t)node * 128 + fo);  // holds -k'
        const int p0 = rowStart[node];
        const int dg = deg[node];
        const int e  = p0 + dg;
        const int eL = e - 1;

        float nkf[8];
        unpack8v(kraw, nkf);
        float acc[8] = {};

        for (int base = p0; base < e; base += 4) {
            int idx[4];
            #pragma unroll
            for (int s = 0; s < 4; ++s) {
                int pp = base + s;
                idx[s] = elist[pp < e ? pp : eL];   // clamped: in-bounds
            }
            u4v qr[4], vr[4];
            #pragma unroll
            for (int s = 0; s < 4; ++s) {
                const unsigned short* r = qvb + (idx[s] << 8);
                qr[s] = *(const u4v*)(r);
                vr[s] = *(const u4v*)(r + 128);
            }
            #pragma unroll
            for (int s = 0; s < 4; ++s) {
                u4v vv = vr[s];
                if (base + s >= e) { vv[0] = 0u; vv[1] = 0u; vv[2] = 0u; vv[3] = 0u; }
                float qf[8], vf[8];
                unpack8v(qr[s], qf);
                unpack8v(vv, vf);
                #pragma unroll
                for (int j = 0; j < 8; ++j) {
                    float ex = __builtin_amdgcn_exp2f(nkf[j] - qf[j]);
                    acc[j] = fmaf(__builtin_amdgcn_rcpf(1.0f + ex), vf[j], acc[j]);
                }
            }
        }

        o0[0] += acc[0]; o0[1] += acc[1]; o0[2] += acc[2]; o0[3] += acc[3];
        o1[0] += acc[4]; o1[1] += acc[5]; o1[2] += acc[6]; o1[3] += acc[7];
        *(f4v*)(orow)     = o0;
        *(f4v*)(orow + 4) = o1;
    }
}

extern "C" void kernel_launch(void* const* d_in, const int* in_sizes, int n_in,
                              void* d_out, int out_size, void* d_ws, size_t ws_size,
                              hipStream_t stream) {
    const float* x    = (const float*)d_in[0];
    const int*   ei   = (const int*)d_in[1];
    const float* Wk   = (const float*)d_in[3];
    const float* bk   = (const float*)d_in[4];
    const float* Wq   = (const float*)d_in[5];
    const float* bq   = (const float*)d_in[6];
    const float* Wv   = (const float*)d_in[7];
    const float* bv   = (const float*)d_in[8];
    const float* Ws   = (const float*)d_in[9];
    const float* bias = (const float*)d_in[10];

    const int N = in_sizes[0] / 128;
    const int E = in_sizes[1] / 2;
    float* out = (float*)d_out;

    // workspace layout
    unsigned short* kws = (unsigned short*)d_ws;        // N*128 bf16 (-k', scaled)
    unsigned short* qv  = kws + (size_t)N * 128;        // N*256 bf16 (q'|v)
    int* deg      = (int*)(qv + (size_t)N * 256);
    int* rowStart = deg + N;
    int* chunkTot = rowStart + N;
    int* pos      = chunkTot + 128;                     // E ints (per-edge slot)
    int* elist    = pos + E;
    unsigned short* Wt = (unsigned short*)(elist + E);

    const int nChunks = (N + 1023) / 1024;
    const int ntiles128 = (N + 127) >> 7;               // 782

    prep_w_zero<<<512, 256, 0, stream>>>(Wk, Wq, Wv, Ws, Wt, deg, N);
    gemm_fused<<<ntiles128, 1024, 0, stream>>>(
        x, N, Wt, bk, bq, bv, bias, kws, qv, out, ei, E, deg, pos);

    scan_chunks<<<nChunks, 256, 0, stream>>>(deg, N, rowStart, chunkTot);
    add_offsets<<<nChunks, 256, 0, stream>>>(rowStart, chunkTot, N, nChunks);
    fill_csr<<<(E + 255) / 256, 256, 0, stream>>>(ei, E, rowStart, pos, elist);

    gather_agg<<<2048, 256, 0, stream>>>(
        rowStart, deg, elist, kws, qv, out, N);
}

// Round 9
// 298.494 us; speedup vs baseline: 1.0200x; 1.0200x over previous
//
#include <hip/hip_runtime.h>
#include <hip/hip_bf16.h>

typedef __bf16 v4bf __attribute__((ext_vector_type(4)));
typedef __bf16 v8bf __attribute__((ext_vector_type(8)));
typedef float  v16f __attribute__((ext_vector_type(16)));
typedef float  f4v  __attribute__((ext_vector_type(4)));
typedef unsigned int u4v __attribute__((ext_vector_type(4)));

#define LOG2E 1.44269504088896340736f

// round-to-nearest-even float -> bf16 bits
__device__ __forceinline__ unsigned short f2bf(float f) {
    union { float f; unsigned int u; } a; a.f = f;
    unsigned int r = a.u + 0x7FFFu + ((a.u >> 16) & 1u);
    return (unsigned short)(r >> 16);
}

__device__ __forceinline__ void unpack8v(u4v w, float* f) {
    #pragma unroll
    for (int i = 0; i < 4; ++i) {
        f[2 * i]     = __uint_as_float(w[i] << 16);
        f[2 * i + 1] = __uint_as_float(w[i] & 0xFFFF0000u);
    }
}

// ---------------- Phase 0: pack W^T bf16 + zero deg (fused) ----------------
// k & q weights pre-scaled by log2(e); k additionally NEGATED so the
// gather kernel reads nk = -k' directly (sigmoid = rcp(1 + 2^(nk - q'))).
__global__ __launch_bounds__(256) void prep_w_zero(
    const float* __restrict__ Wk, const float* __restrict__ Wq,
    const float* __restrict__ Wv, const float* __restrict__ Ws,
    unsigned short* __restrict__ Wt, int* __restrict__ deg, int N)
{
    int i = blockIdx.x * 256 + threadIdx.x;      // 512 blocks -> 131072 threads
    if (i < 65536) {
        int m = i >> 14;
        int r = i & 16383;
        int n = r >> 7, k = r & 127;
        const float* W = (m == 0) ? Wk : (m == 1) ? Wq : (m == 2) ? Wv : Ws;
        float scale = (m == 0) ? -LOG2E : (m == 1) ? LOG2E : 1.0f;
        Wt[i] = f2bf(W[k * 128 + n] * scale);
    }
    if (i < N) deg[i] = 0;
}

// ---------------- Phase 1: fused MFMA GEMM + edge counting ----------------
// R8 post-mortem: 1024-thread blocks (2/CU, 16-wave barrier coupling) left
// every pipe idle. R9: 256-thread blocks (4 waves), one 32-row tile per
// block, 3125 INDEPENDENT blocks -> 4+ blocks/CU in different phases
// overlap staging/compute/epilogue naturally. Wave = matrix m; loops ct
// over 4 col-tiles, W-frags reloaded per ct from L2 (Wt = 128KB, hot).
// Swapped-operand MFMA (R8, verified): lane owns a ROW, epilogue is 4
// contiguous vector stores per ct. Edge count fused at head (1 atomic).
__global__ __launch_bounds__(256, 4) void gemm_fused(
    const float* __restrict__ x, int N,
    const unsigned short* __restrict__ Wt,
    const float* __restrict__ bk, const float* __restrict__ bq,
    const float* __restrict__ bv, const float* __restrict__ bs,
    unsigned short* __restrict__ kws, unsigned short* __restrict__ qv,
    float* __restrict__ out,
    const int* __restrict__ ei, int E,
    int* __restrict__ deg, int* __restrict__ pos)
{
    // fused counting-sort pass 1 (<=1 edge per thread at this grid)
    for (int e = blockIdx.x * 256 + threadIdx.x; e < E; e += gridDim.x * 256) {
        pos[e] = atomicAdd(&deg[ei[E + e]], 1);   // dst
    }

    __shared__ __align__(16) unsigned short xs[32 * 132];
    const int t  = threadIdx.x;
    const int tb = blockIdx.x * 32;              // tile base row

    // ---- stage 32x128 x-tile as bf16 (thread: 1 row-piece of 16 cols) ----
    {
        const int srow = t >> 3;                 // 0..31
        const int scol = (t & 7) << 4;           // 0,16,...,112
        const int gr = tb + srow;
        float4 f0, f1, f2, f3;
        if (gr < N) {
            const float* xp = x + (size_t)gr * 128 + scol;
            f0 = *(const float4*)(xp);
            f1 = *(const float4*)(xp + 4);
            f2 = *(const float4*)(xp + 8);
            f3 = *(const float4*)(xp + 12);
        } else {
            f0 = f1 = f2 = f3 = make_float4(0.f, 0.f, 0.f, 0.f);
        }
        unsigned short* sp = xs + srow * 132 + scol;
        ushort4 p;
        p.x = f2bf(f0.x); p.y = f2bf(f0.y); p.z = f2bf(f0.z); p.w = f2bf(f0.w);
        *(ushort4*)(sp) = p;
        p.x = f2bf(f1.x); p.y = f2bf(f1.y); p.z = f2bf(f1.z); p.w = f2bf(f1.w);
        *(ushort4*)(sp + 4) = p;
        p.x = f2bf(f2.x); p.y = f2bf(f2.y); p.z = f2bf(f2.z); p.w = f2bf(f2.w);
        *(ushort4*)(sp + 8) = p;
        p.x = f2bf(f3.x); p.y = f2bf(f3.y); p.z = f2bf(f3.z); p.w = f2bf(f3.w);
        *(ushort4*)(sp + 12) = p;
    }

    const int m  = t >> 6;           // wave = matrix 0..3
    const int l  = t & 63;
    const int lr = l & 31;           // lane row index within tile
    const int h  = l >> 5;           // half-wave
    const int kb = h * 8;

    const float* bvec = (m == 0) ? bk : (m == 1) ? bq : (m == 2) ? bv : bs;
    const float bscale = (m == 0) ? -LOG2E : (m == 1) ? LOG2E : 1.0f;
    unsigned short* dst; int dstride;
    if (m == 0)      { dst = kws;      dstride = 128; }
    else if (m == 1) { dst = qv;       dstride = 256; }
    else             { dst = qv + 128; dstride = 256; }   // m==2 (v half)

    __syncthreads();

    // ---- x fragments (B operand), read ONCE per tile, reused by all ct ----
    v8bf a[8];
    {
        const unsigned short* ap = xs + lr * 132 + kb;
        #pragma unroll
        for (int c = 0; c < 8; ++c) {
            v4bf a0 = *(const v4bf*)(ap + c * 16);
            v4bf a1 = *(const v4bf*)(ap + c * 16 + 4);
            a[c] = __builtin_shufflevector(a0, a1, 0, 1, 2, 3, 4, 5, 6, 7);
        }
    }

    const int row = tb + lr;

    // ---- 4 col-tiles: reload W-frags (L2-hot), 8 MFMA, vector stores ----
    #pragma unroll
    for (int ct = 0; ct < 4; ++ct) {
        v8bf b[8];
        const unsigned short* wp = Wt + m * 16384 + (ct * 32 + lr) * 128 + kb;
        #pragma unroll
        for (int c = 0; c < 8; ++c) b[c] = *(const v8bf*)(wp + c * 16);

        v16f acc = {};
        #pragma unroll
        for (int c = 0; c < 8; ++c)
            acc = __builtin_amdgcn_mfma_f32_32x32x16_bf16(b[c], a[c], acc, 0, 0, 0);

        // D' = out^T fragment: lane owns row; reg group g -> cols
        // ct*32 + 8g + 4h + 0..3 (contiguous)
        if (row < N) {
            if (m == 3) {
                float* orow = out + (size_t)row * 128 + ct * 32 + 4 * h;
                #pragma unroll
                for (int g = 0; g < 4; ++g) {
                    float4 bb = *(const float4*)(bvec + ct * 32 + 8 * g + 4 * h);
                    float4 o;
                    o.x = acc[4 * g + 0] + bb.x;
                    o.y = acc[4 * g + 1] + bb.y;
                    o.z = acc[4 * g + 2] + bb.z;
                    o.w = acc[4 * g + 3] + bb.w;
                    *(float4*)(orow + 8 * g) = o;
                }
            } else {
                unsigned short* drow = dst + (size_t)row * dstride + ct * 32 + 4 * h;
                #pragma unroll
                for (int g = 0; g < 4; ++g) {
                    float4 bb = *(const float4*)(bvec + ct * 32 + 8 * g + 4 * h);
                    ushort4 p;
                    p.x = f2bf(acc[4 * g + 0] + bb.x * bscale);
                    p.y = f2bf(acc[4 * g + 1] + bb.y * bscale);
                    p.z = f2bf(acc[4 * g + 2] + bb.z * bscale);
                    p.w = f2bf(acc[4 * g + 3] + bb.w * bscale);
                    *(ushort4*)(drow + 8 * g) = p;
                }
            }
        }
    }
}

// ---------------- Phase 2: CSR finish (scan + scatter, atomic-free) ----------------

__global__ __launch_bounds__(256) void scan_chunks(
    const int* __restrict__ deg, int N, int* __restrict__ rowStart,
    int* __restrict__ chunkTot)
{
    __shared__ int sums[256];
    const int t = threadIdx.x;
    const int base = blockIdx.x * 1024 + t * 4;
    int d0 = 0, d1 = 0, d2 = 0, d3 = 0;
    if (base + 3 < N) {
        int4 dd = *(const int4*)(deg + base);
        d0 = dd.x; d1 = dd.y; d2 = dd.z; d3 = dd.w;
    } else {
        if (base + 0 < N) d0 = deg[base + 0];
        if (base + 1 < N) d1 = deg[base + 1];
        if (base + 2 < N) d2 = deg[base + 2];
        if (base + 3 < N) d3 = deg[base + 3];
    }
    int tot = d0 + d1 + d2 + d3;
    sums[t] = tot;
    __syncthreads();
    #pragma unroll
    for (int off = 1; off < 256; off <<= 1) {
        int v = (t >= off) ? sums[t - off] : 0;
        __syncthreads();
        sums[t] += v;
        __syncthreads();
    }
    int excl = sums[t] - tot;
    if (base + 0 < N) rowStart[base + 0] = excl;
    if (base + 1 < N) rowStart[base + 1] = excl + d0;
    if (base + 2 < N) rowStart[base + 2] = excl + d0 + d1;
    if (base + 3 < N) rowStart[base + 3] = excl + d0 + d1 + d2;
    if (t == 255) chunkTot[blockIdx.x] = sums[255];
}

// add chunk offsets; each block re-scans the (<=128) chunk totals in LDS
__global__ __launch_bounds__(256) void add_offsets(
    int* __restrict__ rowStart, const int* __restrict__ chunkTot,
    int N, int nChunks)
{
    __shared__ int s[128];
    const int t = threadIdx.x;
    if (t < 128) s[t] = (t < nChunks) ? chunkTot[t] : 0;
    __syncthreads();
    #pragma unroll
    for (int off = 1; off < 128; off <<= 1) {
        int u = 0;
        if (t < 128 && t >= off) u = s[t - off];
        __syncthreads();
        if (t < 128) s[t] += u;
        __syncthreads();
    }
    const int coff = (blockIdx.x == 0) ? 0 : s[blockIdx.x - 1];
    const int base = blockIdx.x * 1024 + t * 4;
    if (base + 3 < N) {
        int4 r = *(const int4*)(rowStart + base);
        r.x += coff; r.y += coff; r.z += coff; r.w += coff;
        *(int4*)(rowStart + base) = r;
    } else {
        #pragma unroll
        for (int j = 0; j < 4; ++j) {
            if (base + j < N) rowStart[base + j] += coff;
        }
    }
}

__global__ __launch_bounds__(256) void fill_csr(
    const int* __restrict__ ei, int E,
    const int* __restrict__ rowStart, const int* __restrict__ pos,
    int* __restrict__ elist)
{
    int e = blockIdx.x * 256 + threadIdx.x;
    if (e >= E) return;
    elist[rowStart[ei[E + e]] + pos[e]] = ei[e];   // atomic-free scatter
}

// ---------------- Phase 3: owner-computes aggregation (no atomics) ----------------
// R8 post-mortem: (256,8) forced VGPR=32 -> scratch spills (+87MB HBM
// write). Reverted to the R0/R1-proven config: (256,4), ONE-SHOT launch,
// natural node order, out-RMW read hoisted (natural order keeps WRITE at
// 50MB). Body keeps the exact-trip chunk-4 clamp loop (1.16x slot
// inflation vs R1's chunk-8 1.5x, no serial remainder).
__global__ __launch_bounds__(256, 4) void gather_agg(
    const int* __restrict__ rowStart, const int* __restrict__ deg,
    const int* __restrict__ elist,
    const unsigned short* __restrict__ kws,
    const unsigned short* __restrict__ qv,
    float* __restrict__ out, int N)
{
    int gid = blockIdx.x * 256 + threadIdx.x;
    int node = gid >> 4;
    if (node >= N) return;
    const int fo = (gid & 15) << 3;   // 8 feats per lane

    // independent long-latency loads first
    float* orow = out + (size_t)node * 128 + fo;
    f4v o0 = *(const f4v*)(orow);
    f4v o1 = *(const f4v*)(orow + 4);
    u4v kraw = *(const u4v*)(kws + (size_t)node * 128 + fo);  // holds -k'
    const int p0 = rowStart[node];
    const int dg = deg[node];
    const int e  = p0 + dg;
    const int eL = e - 1;

    float nkf[8];
    unpack8v(kraw, nkf);
    float acc[8] = {};

    const unsigned short* qvb = qv + fo;

    for (int base = p0; base < e; base += 4) {
        int idx[4];
        #pragma unroll
        for (int s = 0; s < 4; ++s) {
            int pp = base + s;
            idx[s] = elist[pp < e ? pp : eL];   // clamped: in-bounds
        }
        u4v qr[4], vr[4];
        #pragma unroll
        for (int s = 0; s < 4; ++s) {
            const unsigned short* r = qvb + (idx[s] << 8);
            qr[s] = *(const u4v*)(r);
            vr[s] = *(const u4v*)(r + 128);
        }
        #pragma unroll
        for (int s = 0; s < 4; ++s) {
            u4v vv = vr[s];
            if (base + s >= e) { vv[0] = 0u; vv[1] = 0u; vv[2] = 0u; vv[3] = 0u; }
            float qf[8], vf[8];
            unpack8v(qr[s], qf);
            unpack8v(vv, vf);
            #pragma unroll
            for (int j = 0; j < 8; ++j) {
                float ex = __builtin_amdgcn_exp2f(nkf[j] - qf[j]);
                acc[j] = fmaf(__builtin_amdgcn_rcpf(1.0f + ex), vf[j], acc[j]);
            }
        }
    }

    o0[0] += acc[0]; o0[1] += acc[1]; o0[2] += acc[2]; o0[3] += acc[3];
    o1[0] += acc[4]; o1[1] += acc[5]; o1[2] += acc[6]; o1[3] += acc[7];
    *(f4v*)(orow)     = o0;
    *(f4v*)(orow + 4) = o1;
}

extern "C" void kernel_launch(void* const* d_in, const int* in_sizes, int n_in,
                              void* d_out, int out_size, void* d_ws, size_t ws_size,
                              hipStream_t stream) {
    const float* x    = (const float*)d_in[0];
    const int*   ei   = (const int*)d_in[1];
    const float* Wk   = (const float*)d_in[3];
    const float* bk   = (const float*)d_in[4];
    const float* Wq   = (const float*)d_in[5];
    const float* bq   = (const float*)d_in[6];
    const float* Wv   = (const float*)d_in[7];
    const float* bv   = (const float*)d_in[8];
    const float* Ws   = (const float*)d_in[9];
    const float* bias = (const float*)d_in[10];

    const int N = in_sizes[0] / 128;
    const int E = in_sizes[1] / 2;
    float* out = (float*)d_out;

    // workspace layout
    unsigned short* kws = (unsigned short*)d_ws;        // N*128 bf16 (-k', scaled)
    unsigned short* qv  = kws + (size_t)N * 128;        // N*256 bf16 (q'|v)
    int* deg      = (int*)(qv + (size_t)N * 256);
    int* rowStart = deg + N;
    int* chunkTot = rowStart + N;
    int* pos      = chunkTot + 128;                     // E ints (per-edge slot)
    int* elist    = pos + E;
    unsigned short* Wt = (unsigned short*)(elist + E);

    const int nChunks = (N + 1023) / 1024;
    const int ntiles32 = (N + 31) >> 5;                 // 3125

    prep_w_zero<<<512, 256, 0, stream>>>(Wk, Wq, Wv, Ws, Wt, deg, N);
    gemm_fused<<<ntiles32, 256, 0, stream>>>(
        x, N, Wt, bk, bq, bv, bias, kws, qv, out, ei, E, deg, pos);

    scan_chunks<<<nChunks, 256, 0, stream>>>(deg, N, rowStart, chunkTot);
    add_offsets<<<nChunks, 256, 0, stream>>>(rowStart, chunkTot, N, nChunks);
    fill_csr<<<(E + 255) / 256, 256, 0, stream>>>(ei, E, rowStart, pos, elist);

    gather_agg<<<((size_t)N * 16 + 255) / 256, 256, 0, stream>>>(
        rowStart, deg, elist, kws, qv, out, N);
}

// Round 10
// 264.063 us; speedup vs baseline: 1.1530x; 1.1304x over previous
//
#include <hip/hip_runtime.h>
#include <hip/hip_bf16.h>

typedef __bf16 v4bf __attribute__((ext_vector_type(4)));
typedef __bf16 v8bf __attribute__((ext_vector_type(8)));
typedef float  v16f __attribute__((ext_vector_type(16)));
typedef float  f4v  __attribute__((ext_vector_type(4)));
typedef unsigned int u4v __attribute__((ext_vector_type(4)));

#define LOG2E 1.44269504088896340736f

// round-to-nearest-even float -> bf16 bits
__device__ __forceinline__ unsigned short f2bf(float f) {
    union { float f; unsigned int u; } a; a.f = f;
    unsigned int r = a.u + 0x7FFFu + ((a.u >> 16) & 1u);
    return (unsigned short)(r >> 16);
}

__device__ __forceinline__ void unpack8v(u4v w, float* f) {
    #pragma unroll
    for (int i = 0; i < 4; ++i) {
        f[2 * i]     = __uint_as_float(w[i] << 16);
        f[2 * i + 1] = __uint_as_float(w[i] & 0xFFFF0000u);
    }
}

// ---------------- Phase 0: pack W^T bf16 + edge count (fused) ----------------
// deg zeroed by hipMemsetAsync before this kernel. k & q weights pre-scaled
// by log2(e); k negated so gather reads nk = -k' directly.
// count_pos fused here (R7 proved head-fusion of VMEM/atomic work ~free).
__global__ __launch_bounds__(256) void prep_count(
    const float* __restrict__ Wk, const float* __restrict__ Wq,
    const float* __restrict__ Wv, const float* __restrict__ Ws,
    unsigned short* __restrict__ Wt,
    const int* __restrict__ ei, int E,
    int* __restrict__ deg, int* __restrict__ pos)
{
    int i = blockIdx.x * 256 + threadIdx.x;      // 512 blocks -> 131072 threads
    if (i < 65536) {
        int m = i >> 14;
        int r = i & 16383;
        int n = r >> 7, k = r & 127;
        const float* W = (m == 0) ? Wk : (m == 1) ? Wq : (m == 2) ? Wv : Ws;
        float scale = (m == 0) ? -LOG2E : (m == 1) ? LOG2E : 1.0f;
        Wt[i] = f2bf(W[k * 128 + n] * scale);
    }
    for (int e = i; e < E; e += 131072) {
        pos[e] = atomicAdd(&deg[ei[E + e]], 1);   // dst; counting-sort pass 1
    }
}

// ---------------- Phase 1: single-kernel CSR scan (publish + lookback) ----------------
// Replaces scan_chunks + add_offsets (one launch boundary saved). Each of
// the 98 blocks scans its 1024-deg chunk, PUBLISHES its total (flag =
// total+1, device-scope, after threadfence), then spin-reads all
// predecessor flags. Publish-before-spin => no circular wait; 98 blocks
// are trivially co-resident on 256 CUs.
__global__ __launch_bounds__(256) void scan_fused(
    const int* __restrict__ deg, int N, int* __restrict__ rowStart,
    int* __restrict__ flag)
{
    __shared__ int sums[256];
    __shared__ int red[256];
    const int t = threadIdx.x;
    const int b = blockIdx.x;
    const int base = b * 1024 + t * 4;
    int d0 = 0, d1 = 0, d2 = 0, d3 = 0;
    if (base + 3 < N) {
        int4 dd = *(const int4*)(deg + base);
        d0 = dd.x; d1 = dd.y; d2 = dd.z; d3 = dd.w;
    } else {
        if (base + 0 < N) d0 = deg[base + 0];
        if (base + 1 < N) d1 = deg[base + 1];
        if (base + 2 < N) d2 = deg[base + 2];
        if (base + 3 < N) d3 = deg[base + 3];
    }
    int tot = d0 + d1 + d2 + d3;
    sums[t] = tot;
    __syncthreads();
    #pragma unroll
    for (int off = 1; off < 256; off <<= 1) {
        int v = (t >= off) ? sums[t - off] : 0;
        __syncthreads();
        sums[t] += v;
        __syncthreads();
    }
    // publish own chunk total (nonzero sentinel: total+1)
    if (t == 255) {
        __threadfence();
        atomicExch(&flag[b], sums[255] + 1);
    }
    // lookback: spin on predecessor flags (each publishes before spinning)
    int partial = 0;
    for (int j = t; j < b; j += 256) {
        int v;
        do { v = atomicAdd(&flag[j], 0); } while (v == 0);
        partial += v - 1;
    }
    red[t] = partial;
    __syncthreads();
    #pragma unroll
    for (int off = 128; off > 0; off >>= 1) {
        if (t < off) red[t] += red[t + off];
        __syncthreads();
    }
    const int coff = red[0];
    int excl = sums[t] - tot + coff;
    if (base + 0 < N) rowStart[base + 0] = excl;
    if (base + 1 < N) rowStart[base + 1] = excl + d0;
    if (base + 2 < N) rowStart[base + 2] = excl + d0 + d1;
    if (base + 3 < N) rowStart[base + 3] = excl + d0 + d1 + d2;
}

// ---------------- Phase 2: fused MFMA GEMM + CSR scatter ----------------
// EXACT R6 gemm structure (measured <=77us there; R8/R9 "improvements"
// regressed to 104/120 — reverted). 1024 threads = 16 waves = 16 (mat,
// col-tile) combos; B-frags register-resident loaded ONCE; grid-stride
// over 32-row x-tiles staged in LDS (stride 132); next tile prefetched.
// fill_csr's atomic-free scatter fused at head (hides under GEMM).
__global__ __launch_bounds__(1024, 4) void gemm_fill(
    const float* __restrict__ x, int N,
    const unsigned short* __restrict__ Wt,
    const float* __restrict__ bk, const float* __restrict__ bq,
    const float* __restrict__ bv, const float* __restrict__ bs,
    unsigned short* __restrict__ kws, unsigned short* __restrict__ qv,
    float* __restrict__ out,
    const int* __restrict__ ei, int E,
    const int* __restrict__ rowStart, const int* __restrict__ pos,
    int* __restrict__ elist)
{
    // fused counting-sort pass 2: scatter src ids into CSR slots
    for (int e = blockIdx.x * 1024 + threadIdx.x; e < E; e += gridDim.x * 1024) {
        elist[rowStart[ei[E + e]] + pos[e]] = ei[e];
    }

    __shared__ __align__(16) unsigned short xs[32 * 132];
    const int t   = threadIdx.x;
    const int wid = t >> 6;          // 0..15
    const int m   = wid >> 2;        // matrix
    const int ct  = wid & 3;         // col tile
    const int l   = t & 63;
    const int col = ct * 32 + (l & 31);
    const int kb  = (l >> 5) * 8;

    v8bf b[8];
    {
        const unsigned short* wp = Wt + m * 16384 + col * 128 + kb;
        #pragma unroll
        for (int c = 0; c < 8; ++c) b[c] = *(const v8bf*)(wp + c * 16);
    }
    const float* bvec = (m == 0) ? bk : (m == 1) ? bq : (m == 2) ? bv : bs;
    const float bcol = bvec[col] * ((m == 0) ? -LOG2E : (m == 1) ? LOG2E : 1.0f);
    unsigned short* dst; int dstride;
    if (m == 0)      { dst = kws;      dstride = 128; }
    else if (m == 1) { dst = qv;       dstride = 256; }
    else             { dst = qv + 128; dstride = 256; }   // m==2 (v half)

    const int srow = t >> 5;         // 0..31
    const int sk4  = (t & 31) << 2;  // 0..124
    const int rowb = 4 * (l >> 5);

    const int ntiles = (N + 31) >> 5;
    int tile = blockIdx.x;
    if (tile >= ntiles) return;

    float4 stg = make_float4(0.f, 0.f, 0.f, 0.f);
    {
        int gr = tile * 32 + srow;
        if (gr < N) stg = *(const float4*)(x + (size_t)gr * 128 + sk4);
    }

    const unsigned short* ap = xs + (l & 31) * 132 + kb;

    while (true) {
        ushort4 pk;
        pk.x = f2bf(stg.x); pk.y = f2bf(stg.y);
        pk.z = f2bf(stg.z); pk.w = f2bf(stg.w);
        *(ushort4*)(xs + srow * 132 + sk4) = pk;
        __syncthreads();

        int next = tile + gridDim.x;
        if (next < ntiles) {
            int gr = next * 32 + srow;
            stg = (gr < N) ? *(const float4*)(x + (size_t)gr * 128 + sk4)
                           : make_float4(0.f, 0.f, 0.f, 0.f);
        }

        v16f acc = {};
        #pragma unroll
        for (int c = 0; c < 8; ++c) {
            v4bf a0 = *(const v4bf*)(ap + c * 16);
            v4bf a1 = *(const v4bf*)(ap + c * 16 + 4);
            v8bf a = __builtin_shufflevector(a0, a1, 0, 1, 2, 3, 4, 5, 6, 7);
            acc = __builtin_amdgcn_mfma_f32_32x32x16_bf16(a, b[c], acc, 0, 0, 0);
        }

        // C/D: col = lane&31, row = (reg&3) + 8*(reg>>2) + 4*(lane>>5)
        const int r0 = tile * 32 + rowb;
        if (m == 3) {
            #pragma unroll
            for (int reg = 0; reg < 16; ++reg) {
                int row = r0 + (reg & 3) + 8 * (reg >> 2);
                if (row < N) out[(size_t)row * 128 + col] = acc[reg] + bcol;
            }
        } else {
            #pragma unroll
            for (int reg = 0; reg < 16; ++reg) {
                int row = r0 + (reg & 3) + 8 * (reg >> 2);
                if (row < N) dst[(size_t)row * dstride + col] = f2bf(acc[reg] + bcol);
            }
        }

        tile = next;
        if (tile >= ntiles) break;
        __syncthreads();
    }
}

// ---------------- Phase 3: owner-computes aggregation (no atomics) ----------------
// R0/R1-proven config: (256,4), one-shot launch, natural node order,
// out-RMW read hoisted. Exact-trip chunk-4 clamp loop (1.16x inflation).
__global__ __launch_bounds__(256, 4) void gather_agg(
    const int* __restrict__ rowStart, const int* __restrict__ deg,
    const int* __restrict__ elist,
    const unsigned short* __restrict__ kws,
    const unsigned short* __restrict__ qv,
    float* __restrict__ out, int N)
{
    int gid = blockIdx.x * 256 + threadIdx.x;
    int node = gid >> 4;
    if (node >= N) return;
    const int fo = (gid & 15) << 3;   // 8 feats per lane

    // independent long-latency loads first
    float* orow = out + (size_t)node * 128 + fo;
    f4v o0 = *(const f4v*)(orow);
    f4v o1 = *(const f4v*)(orow + 4);
    u4v kraw = *(const u4v*)(kws + (size_t)node * 128 + fo);  // holds -k'
    const int p0 = rowStart[node];
    const int dg = deg[node];
    const int e  = p0 + dg;
    const int eL = e - 1;

    float nkf[8];
    unpack8v(kraw, nkf);
    float acc[8] = {};

    const unsigned short* qvb = qv + fo;

    for (int base = p0; base < e; base += 4) {
        int idx[4];
        #pragma unroll
        for (int s = 0; s < 4; ++s) {
            int pp = base + s;
            idx[s] = elist[pp < e ? pp : eL];   // clamped: in-bounds
        }
        u4v qr[4], vr[4];
        #pragma unroll
        for (int s = 0; s < 4; ++s) {
            const unsigned short* r = qvb + (idx[s] << 8);
            qr[s] = *(const u4v*)(r);
            vr[s] = *(const u4v*)(r + 128);
        }
        #pragma unroll
        for (int s = 0; s < 4; ++s) {
            u4v vv = vr[s];
            if (base + s >= e) { vv[0] = 0u; vv[1] = 0u; vv[2] = 0u; vv[3] = 0u; }
            float qf[8], vf[8];
            unpack8v(qr[s], qf);
            unpack8v(vv, vf);
            #pragma unroll
            for (int j = 0; j < 8; ++j) {
                float ex = __builtin_amdgcn_exp2f(nkf[j] - qf[j]);
                acc[j] = fmaf(__builtin_amdgcn_rcpf(1.0f + ex), vf[j], acc[j]);
            }
        }
    }

    o0[0] += acc[0]; o0[1] += acc[1]; o0[2] += acc[2]; o0[3] += acc[3];
    o1[0] += acc[4]; o1[1] += acc[5]; o1[2] += acc[6]; o1[3] += acc[7];
    *(f4v*)(orow)     = o0;
    *(f4v*)(orow + 4) = o1;
}

extern "C" void kernel_launch(void* const* d_in, const int* in_sizes, int n_in,
                              void* d_out, int out_size, void* d_ws, size_t ws_size,
                              hipStream_t stream) {
    const float* x    = (const float*)d_in[0];
    const int*   ei   = (const int*)d_in[1];
    const float* Wk   = (const float*)d_in[3];
    const float* bk   = (const float*)d_in[4];
    const float* Wq   = (const float*)d_in[5];
    const float* bq   = (const float*)d_in[6];
    const float* Wv   = (const float*)d_in[7];
    const float* bv   = (const float*)d_in[8];
    const float* Ws   = (const float*)d_in[9];
    const float* bias = (const float*)d_in[10];

    const int N = in_sizes[0] / 128;
    const int E = in_sizes[1] / 2;
    float* out = (float*)d_out;

    // workspace layout
    unsigned short* kws = (unsigned short*)d_ws;        // N*128 bf16 (-k', scaled)
    unsigned short* qv  = kws + (size_t)N * 128;        // N*256 bf16 (q'|v)
    int* deg      = (int*)(qv + (size_t)N * 256);       // [N] + flags[128] contig
    int* flag     = deg + N;                            // 128 ints (chunk flags)
    int* rowStart = flag + 128;
    int* pos      = rowStart + N;                       // E ints (per-edge slot)
    int* elist    = pos + E;
    unsigned short* Wt = (unsigned short*)(elist + E);

    const int nChunks = (N + 1023) / 1024;              // 98

    // zero deg + flags in one stream-ordered memset (graph-capturable)
    hipMemsetAsync(deg, 0, (size_t)(N + 128) * sizeof(int), stream);

    prep_count<<<512, 256, 0, stream>>>(Wk, Wq, Wv, Ws, Wt, ei, E, deg, pos);
    scan_fused<<<nChunks, 256, 0, stream>>>(deg, N, rowStart, flag);
    gemm_fill<<<1024, 1024, 0, stream>>>(
        x, N, Wt, bk, bq, bv, bias, kws, qv, out, ei, E, rowStart, pos, elist);
    gather_agg<<<((size_t)N * 16 + 255) / 256, 256, 0, stream>>>(
        rowStart, deg, elist, kws, qv, out, N);
}